// Round 5
// baseline (99.512 us; speedup 1.0000x reference)
//
#include <hip/hip_runtime.h>
#include <hip/hip_bf16.h>

// Continuous-filter convolution (SchNet-style), MI355X gfx950.
// M_ij = relu(relu(rbf(D_ij)@W1)@W2) depends only on scalar D_ij in [0, R^2).
// Build a T-point bf16 pair-table of F(D) on-device (MFMA pipeline), then the
// main kernel is lerp + gather(X[src]) + run-length-reduced atomic scatter.
#define HIDDEN 256
#define NB 128
#define TE 64           // grid rows per build workgroup
#define TEB 128         // edges per gather workgroup
#define E_TOTAL 262144
#define V_TOTAL 32768
#define R2MAX 2.25f

typedef __attribute__((ext_vector_type(8))) __bf16 bf16x8;
typedef __attribute__((ext_vector_type(4))) float floatx4;

__device__ inline unsigned short f2bf(float f) {
    union { float f; unsigned u; } v; v.f = f;
    unsigned r = v.u + 0x7fffu + ((v.u >> 16) & 1u);   // RNE
    return (unsigned short)(r >> 16);
}

// Fused setup: zero the output (float4 stores) + transpose/convert weights.
//   W1T[c][k] = bf16(W1[k][c])   c<256, k<128
//   W2T[c][k] = bf16(W2[k][c])   c<256, k<256
__global__ __launch_bounds__(256)
void cfconv_setup(const float* __restrict__ W1,
                  const float* __restrict__ W2,
                  unsigned short* __restrict__ wbuf,
                  float4* __restrict__ out4, int nout4) {
    int id = blockIdx.x * 256 + threadIdx.x;
    if (id < nout4) out4[id] = make_float4(0.f, 0.f, 0.f, 0.f);
    if (id < NB * HIDDEN) {
        int c = id >> 7, k = id & (NB - 1);
        wbuf[id] = f2bf(W1[k * HIDDEN + c]);
    }
    int id2 = id - NB * HIDDEN;
    if (id2 >= 0 && id2 < HIDDEN * HIDDEN) {
        int c = id2 >> 8, k = id2 & (HIDDEN - 1);
        wbuf[NB * HIDDEN + id2] = f2bf(W2[k * HIDDEN + c]);
    }
}

// Build the F(D) table at grid points D_i = i*invScale, i in [0,T).
// tab16 is a u16 view of the u32 pair table: pair[i][c] = lo:M[i][c], hi:M[i+1][c].
__global__ __launch_bounds__(256, 4)
void cfconv_build(const unsigned short* __restrict__ W1T,
                  const unsigned short* __restrict__ W2T,
                  const float* __restrict__ mu,
                  unsigned short* __restrict__ tab16,
                  float invScale) {
    __shared__ __align__(16) float mulds[NB];
    __shared__ __align__(16) unsigned short h_lds[TE * HIDDEN];   // 32 KB swizzled; h then M

    const int t = threadIdx.x;
    const int eb = blockIdx.x * TE;

    if (t < NB) mulds[t] = mu[t];
    __syncthreads();

    const int lane = t & 63;
    const int w = t >> 6;
    const int lhi = lane >> 4;
    const int llo = lane & 15;

    // ---- GEMM1: h = relu(rbf @ W1), rbf computed in-register from grid D ----
    {
        float dm = mulds[1] - mulds[0];
        float ng = -1.0f / (dm * dm);
        float Dm[4];
        #pragma unroll
        for (int m = 0; m < 4; ++m) Dm[m] = (float)(eb + 16 * m + llo) * invScale;

        floatx4 acc[4][4];
        #pragma unroll
        for (int m = 0; m < 4; ++m)
            #pragma unroll
            for (int n = 0; n < 4; ++n)
                acc[m][n] = (floatx4)(0.0f);

        #pragma unroll
        for (int kc = 0; kc < 4; ++kc) {
            floatx4 mu0 = *(const floatx4*)(mulds + kc * 32 + lhi * 8);
            floatx4 mu1 = *(const floatx4*)(mulds + kc * 32 + lhi * 8 + 4);
            bf16x8 a[4], b[4];
            #pragma unroll
            for (int m = 0; m < 4; ++m) {
                float D = Dm[m];
                #pragma unroll
                for (int j = 0; j < 8; ++j) {
                    float mv = (j < 4) ? mu0[j] : mu1[j - 4];
                    float d = D - mv;
                    a[m][j] = (__bf16)__expf(ng * d * d);
                }
            }
            #pragma unroll
            for (int n = 0; n < 4; ++n) {
                int col = w * 64 + 16 * n + llo;
                b[n] = *(const bf16x8*)(W1T + col * NB + kc * 32 + lhi * 8);
            }
            #pragma unroll
            for (int m = 0; m < 4; ++m)
                #pragma unroll
                for (int n = 0; n < 4; ++n)
                    acc[m][n] = __builtin_amdgcn_mfma_f32_16x16x32_bf16(a[m], b[n], acc[m][n], 0, 0, 0);
        }

        char* hb = (char*)h_lds;
        #pragma unroll
        for (int m = 0; m < 4; ++m)
            #pragma unroll
            for (int n = 0; n < 4; ++n) {
                int col = w * 64 + 16 * n + llo;
                #pragma unroll
                for (int r = 0; r < 4; ++r) {
                    int row = 16 * m + 4 * lhi + r;
                    float v = fmaxf(acc[m][n][r], 0.0f);
                    int byteoff = row * (HIDDEN * 2) + ((col * 2) ^ ((row & 7) << 4));
                    *(__bf16*)(hb + byteoff) = (__bf16)v;
                }
            }
    }
    __syncthreads();

    // ---- GEMM2: M = relu(h @ W2) ----
    floatx4 acc[4][4];
    {
        #pragma unroll
        for (int m = 0; m < 4; ++m)
            #pragma unroll
            for (int n = 0; n < 4; ++n)
                acc[m][n] = (floatx4)(0.0f);

        const char* hb = (const char*)h_lds;
        #pragma unroll
        for (int kc = 0; kc < 8; ++kc) {
            bf16x8 a[4], b[4];
            #pragma unroll
            for (int m = 0; m < 4; ++m) {
                int row = 16 * m + llo;
                int byteoff = row * (HIDDEN * 2) + ((kc * 64 + 16 * lhi) ^ ((row & 7) << 4));
                a[m] = *(const bf16x8*)(hb + byteoff);
            }
            #pragma unroll
            for (int n = 0; n < 4; ++n) {
                int col = w * 64 + 16 * n + llo;
                b[n] = *(const bf16x8*)(W2T + col * HIDDEN + kc * 32 + lhi * 8);
            }
            #pragma unroll
            for (int m = 0; m < 4; ++m)
                #pragma unroll
                for (int n = 0; n < 4; ++n)
                    acc[m][n] = __builtin_amdgcn_mfma_f32_16x16x32_bf16(a[m], b[n], acc[m][n], 0, 0, 0);
        }
    }
    __syncthreads();   // done reading h_lds

    // ---- store relu(M) bf16 into h_lds (swizzled) ----
    {
        char* hb = (char*)h_lds;
        #pragma unroll
        for (int m = 0; m < 4; ++m)
            #pragma unroll
            for (int n = 0; n < 4; ++n) {
                int col = w * 64 + 16 * n + llo;
                #pragma unroll
                for (int r = 0; r < 4; ++r) {
                    int row = 16 * m + 4 * lhi + r;
                    float v = fmaxf(acc[m][n][r], 0.0f);
                    int byteoff = row * (HIDDEN * 2) + ((col * 2) ^ ((row & 7) << 4));
                    *(__bf16*)(hb + byteoff) = (__bf16)v;
                }
            }
    }
    __syncthreads();

    // ---- write pair table: thread owns column c=t ----
    {
        const char* hb = (const char*)h_lds;
        const int c = t;
        for (int r = 0; r < TE; ++r) {
            unsigned short m16 = *(const unsigned short*)(hb + r * (HIDDEN * 2) + ((2 * c) ^ ((r & 7) << 4)));
            int i = eb + r;
            tab16[((size_t)i * HIDDEN + c) * 2] = m16;               // lo of pair[i]
            if (i > 0)
                tab16[((size_t)(i - 1) * HIDDEN + c) * 2 + 1] = m16; // hi of pair[i-1]
        }
    }
}

// Main: per edge, lerp table -> * X[src] -> run-length reduced atomic add.
// Block = 256 threads, 128 edges. Half h = t>>7 walks edges [64h, 64h+64);
// thread owns 2 adjacent columns c0 = 2*(t&127). Edge meta packed in uint4 LDS.
__global__ __launch_bounds__(256)
void cfconv_gather(const float* __restrict__ X,
                   const float* __restrict__ R,
                   const unsigned int* __restrict__ tab,
                   const int* __restrict__ src,
                   const int* __restrict__ dest,
                   float* __restrict__ out,
                   float scale, int Tm2) {
    __shared__ __align__(16) uint4 meta[TEB];   // {dest, src_byteoff, tab_byteoff, frac-bits}

    const int t = threadIdx.x;
    // XCD-aware swizzle: 2048 blocks, 8 XCDs -> contiguous 256-block chunk per XCD
    const int orig = blockIdx.x;
    const int cpx = gridDim.x >> 3;
    const int wg = (orig & 7) * cpx + (orig >> 3);
    const int eb = wg * TEB;

    if (t < TEB) {
        int e = eb + t;
        int s = src[e], d = dest[e];
        float dx = R[s * 3 + 0] - R[d * 3 + 0];
        float dy = R[s * 3 + 1] - R[d * 3 + 1];
        float dz = R[s * 3 + 2] - R[d * 3 + 2];
        float D = dx * dx + dy * dy + dz * dz;
        float u = D * scale;
        int i0 = min((int)u, Tm2);
        float frac = u - (float)i0;
        uint4 mrec;
        mrec.x = (unsigned)d;
        mrec.y = (unsigned)s * (HIDDEN * 4);           // byte offset into X
        mrec.z = (unsigned)i0 * (HIDDEN * 4);          // byte offset into tab
        mrec.w = __float_as_uint(frac);
        meta[t] = mrec;
    }
    __syncthreads();

    const int rbase = (t >> 7) * 64;          // half 0 / half 1
    const int c0 = (t & 127) * 2;             // two adjacent columns
    const char* tabc = (const char*)tab + c0 * 4;
    const char* Xc = (const char*)X + c0 * 4;

    float racc0 = 0.0f, racc1 = 0.0f;
    int dprev = __builtin_amdgcn_readfirstlane((int)meta[rbase].x);
    #pragma unroll 8
    for (int r = 0; r < 64; ++r) {
        uint4 mrec = meta[rbase + r];                       // broadcast ds_read_b128
        int d = __builtin_amdgcn_readfirstlane((int)mrec.x);
        unsigned soff = __builtin_amdgcn_readfirstlane(mrec.y);
        unsigned ioff = __builtin_amdgcn_readfirstlane(mrec.z);
        float frac = __uint_as_float(__builtin_amdgcn_readfirstlane(mrec.w));
        uint2 pair = *(const uint2*)(tabc + ioff);
        float2 x = *(const float2*)(Xc + soff);
        if (d != dprev) {
            float* orow = out + (size_t)dprev * HIDDEN + c0;
            unsafeAtomicAdd(orow, racc0);
            unsafeAtomicAdd(orow + 1, racc1);
            racc0 = racc1 = 0.0f;
            dprev = d;
        }
        union { unsigned u; float f; } lo0, hi0, lo1, hi1;
        lo0.u = pair.x << 16; hi0.u = pair.x & 0xffff0000u;
        lo1.u = pair.y << 16; hi1.u = pair.y & 0xffff0000u;
        float m0 = fmaf(frac, hi0.f - lo0.f, lo0.f);
        float m1 = fmaf(frac, hi1.f - lo1.f, lo1.f);
        racc0 = fmaf(m0, x.x, racc0);
        racc1 = fmaf(m1, x.y, racc1);
    }
    float* orow = out + (size_t)dprev * HIDDEN + c0;
    unsafeAtomicAdd(orow, racc0);
    unsafeAtomicAdd(orow + 1, racc1);
}

extern "C" void kernel_launch(void* const* d_in, const int* in_sizes, int n_in,
                              void* d_out, int out_size, void* d_ws, size_t ws_size,
                              hipStream_t stream) {
    const float* X  = (const float*)d_in[0];
    const float* R  = (const float*)d_in[1];
    const float* W1 = (const float*)d_in[2];
    const float* W2 = (const float*)d_in[3];
    const float* mu = (const float*)d_in[4];
    const int* src  = (const int*)d_in[5];
    const int* dest = (const int*)d_in[6];
    float* out = (float*)d_out;

    // workspace layout: W1T bf16 | W2T bf16 | pair table u32[T*256]
    unsigned short* W1T = (unsigned short*)d_ws;
    unsigned short* W2T = W1T + NB * HIDDEN;
    unsigned int*   tab = (unsigned int*)(W2T + HIDDEN * HIDDEN);

    const size_t fixed = (size_t)(NB * HIDDEN + HIDDEN * HIDDEN) * 2;
    int T = 2048;
    if (ws_size > 0) {
        while (T > 64 && fixed + (size_t)T * HIDDEN * 4 > ws_size) T >>= 1;
    }
    const float scale = (float)(T - 1) / R2MAX;
    const float invScale = R2MAX / (float)(T - 1);

    int nout4 = out_size / 4;
    int setup_blocks = (nout4 + 255) / 256;
    if (setup_blocks < (NB * HIDDEN + HIDDEN * HIDDEN + 255) / 256)
        setup_blocks = (NB * HIDDEN + HIDDEN * HIDDEN + 255) / 256;

    cfconv_setup<<<setup_blocks, 256, 0, stream>>>(W1, W2, W1T, (float4*)out, nout4);

    cfconv_build<<<T / TE, 256, 0, stream>>>(W1T, W2T, mu, (unsigned short*)tab, invScale);

    cfconv_gather<<<E_TOTAL / TEB, 256, 0, stream>>>(X, R, tab, src, dest, out,
                                                     scale, T - 2);
}

// Round 6
// 74.982 us; speedup vs baseline: 1.3272x; 1.3272x over previous
//
#include <hip/hip_runtime.h>
#include <hip/hip_bf16.h>

// Continuous-filter convolution (SchNet-style), MI355X gfx950.
// M_ij = relu(relu(rbf(D_ij)@W1)@W2) depends only on scalar D_ij in [0, R^2).
// Build a T-point bf16 pair-table of F(D) on-device (MFMA pipeline), then the
// main kernel is lerp + gather(X[src]) + run-length-reduced atomic scatter.
#define HIDDEN 256
#define NB 128
#define TE 64           // grid rows per build workgroup
#define TEB 128         // edges per gather workgroup
#define E_TOTAL 262144
#define V_TOTAL 32768
#define R2MAX 2.25f

typedef __attribute__((ext_vector_type(8))) __bf16 bf16x8;
typedef __attribute__((ext_vector_type(4))) float floatx4;

__device__ inline unsigned short f2bf(float f) {
    union { float f; unsigned u; } v; v.f = f;
    unsigned r = v.u + 0x7fffu + ((v.u >> 16) & 1u);   // RNE
    return (unsigned short)(r >> 16);
}

// Fused setup: zero the output (float4 stores) + transpose/convert weights.
//   W1T[c][k] = bf16(W1[k][c])   c<256, k<128
//   W2T[c][k] = bf16(W2[k][c])   c<256, k<256
__global__ __launch_bounds__(256)
void cfconv_setup(const float* __restrict__ W1,
                  const float* __restrict__ W2,
                  unsigned short* __restrict__ wbuf,
                  float4* __restrict__ out4, int nout4) {
    int id = blockIdx.x * 256 + threadIdx.x;
    if (id < nout4) out4[id] = make_float4(0.f, 0.f, 0.f, 0.f);
    if (id < NB * HIDDEN) {
        int c = id >> 7, k = id & (NB - 1);
        wbuf[id] = f2bf(W1[k * HIDDEN + c]);
    }
    int id2 = id - NB * HIDDEN;
    if (id2 >= 0 && id2 < HIDDEN * HIDDEN) {
        int c = id2 >> 8, k = id2 & (HIDDEN - 1);
        wbuf[NB * HIDDEN + id2] = f2bf(W2[k * HIDDEN + c]);
    }
}

// Build the F(D) table at grid points D_i = i*invScale, i in [0,T).
// tab16 is a u16 view of the u32 pair table: pair[i][c] = lo:M[i][c], hi:M[i+1][c].
__global__ __launch_bounds__(256, 4)
void cfconv_build(const unsigned short* __restrict__ W1T,
                  const unsigned short* __restrict__ W2T,
                  const float* __restrict__ mu,
                  unsigned short* __restrict__ tab16,
                  float invScale) {
    __shared__ __align__(16) float mulds[NB];
    __shared__ __align__(16) unsigned short h_lds[TE * HIDDEN];   // 32 KB swizzled; h then M

    const int t = threadIdx.x;
    const int eb = blockIdx.x * TE;

    if (t < NB) mulds[t] = mu[t];
    __syncthreads();

    const int lane = t & 63;
    const int w = t >> 6;
    const int lhi = lane >> 4;
    const int llo = lane & 15;

    // ---- GEMM1: h = relu(rbf @ W1), rbf computed in-register from grid D ----
    {
        float dm = mulds[1] - mulds[0];
        float ng = -1.0f / (dm * dm);
        float Dm[4];
        #pragma unroll
        for (int m = 0; m < 4; ++m) Dm[m] = (float)(eb + 16 * m + llo) * invScale;

        floatx4 acc[4][4];
        #pragma unroll
        for (int m = 0; m < 4; ++m)
            #pragma unroll
            for (int n = 0; n < 4; ++n)
                acc[m][n] = (floatx4)(0.0f);

        #pragma unroll
        for (int kc = 0; kc < 4; ++kc) {
            floatx4 mu0 = *(const floatx4*)(mulds + kc * 32 + lhi * 8);
            floatx4 mu1 = *(const floatx4*)(mulds + kc * 32 + lhi * 8 + 4);
            bf16x8 a[4], b[4];
            #pragma unroll
            for (int m = 0; m < 4; ++m) {
                float D = Dm[m];
                #pragma unroll
                for (int j = 0; j < 8; ++j) {
                    float mv = (j < 4) ? mu0[j] : mu1[j - 4];
                    float d = D - mv;
                    a[m][j] = (__bf16)__expf(ng * d * d);
                }
            }
            #pragma unroll
            for (int n = 0; n < 4; ++n) {
                int col = w * 64 + 16 * n + llo;
                b[n] = *(const bf16x8*)(W1T + col * NB + kc * 32 + lhi * 8);
            }
            #pragma unroll
            for (int m = 0; m < 4; ++m)
                #pragma unroll
                for (int n = 0; n < 4; ++n)
                    acc[m][n] = __builtin_amdgcn_mfma_f32_16x16x32_bf16(a[m], b[n], acc[m][n], 0, 0, 0);
        }

        char* hb = (char*)h_lds;
        #pragma unroll
        for (int m = 0; m < 4; ++m)
            #pragma unroll
            for (int n = 0; n < 4; ++n) {
                int col = w * 64 + 16 * n + llo;
                #pragma unroll
                for (int r = 0; r < 4; ++r) {
                    int row = 16 * m + 4 * lhi + r;
                    float v = fmaxf(acc[m][n][r], 0.0f);
                    int byteoff = row * (HIDDEN * 2) + ((col * 2) ^ ((row & 7) << 4));
                    *(__bf16*)(hb + byteoff) = (__bf16)v;
                }
            }
    }
    __syncthreads();

    // ---- GEMM2: M = relu(h @ W2) ----
    floatx4 acc[4][4];
    {
        #pragma unroll
        for (int m = 0; m < 4; ++m)
            #pragma unroll
            for (int n = 0; n < 4; ++n)
                acc[m][n] = (floatx4)(0.0f);

        const char* hb = (const char*)h_lds;
        #pragma unroll
        for (int kc = 0; kc < 8; ++kc) {
            bf16x8 a[4], b[4];
            #pragma unroll
            for (int m = 0; m < 4; ++m) {
                int row = 16 * m + llo;
                int byteoff = row * (HIDDEN * 2) + ((kc * 64 + 16 * lhi) ^ ((row & 7) << 4));
                a[m] = *(const bf16x8*)(hb + byteoff);
            }
            #pragma unroll
            for (int n = 0; n < 4; ++n) {
                int col = w * 64 + 16 * n + llo;
                b[n] = *(const bf16x8*)(W2T + col * HIDDEN + kc * 32 + lhi * 8);
            }
            #pragma unroll
            for (int m = 0; m < 4; ++m)
                #pragma unroll
                for (int n = 0; n < 4; ++n)
                    acc[m][n] = __builtin_amdgcn_mfma_f32_16x16x32_bf16(a[m], b[n], acc[m][n], 0, 0, 0);
        }
    }
    __syncthreads();   // done reading h_lds

    // ---- store relu(M) bf16 into h_lds (swizzled) ----
    {
        char* hb = (char*)h_lds;
        #pragma unroll
        for (int m = 0; m < 4; ++m)
            #pragma unroll
            for (int n = 0; n < 4; ++n) {
                int col = w * 64 + 16 * n + llo;
                #pragma unroll
                for (int r = 0; r < 4; ++r) {
                    int row = 16 * m + 4 * lhi + r;
                    float v = fmaxf(acc[m][n][r], 0.0f);
                    int byteoff = row * (HIDDEN * 2) + ((col * 2) ^ ((row & 7) << 4));
                    *(__bf16*)(hb + byteoff) = (__bf16)v;
                }
            }
    }
    __syncthreads();

    // ---- write pair table: thread owns column c=t ----
    {
        const char* hb = (const char*)h_lds;
        const int c = t;
        for (int r = 0; r < TE; ++r) {
            unsigned short m16 = *(const unsigned short*)(hb + r * (HIDDEN * 2) + ((2 * c) ^ ((r & 7) << 4)));
            int i = eb + r;
            tab16[((size_t)i * HIDDEN + c) * 2] = m16;               // lo of pair[i]
            if (i > 0)
                tab16[((size_t)(i - 1) * HIDDEN + c) * 2 + 1] = m16; // hi of pair[i-1]
        }
    }
}

// Main: per edge, lerp table -> * X[src] -> run-length reduced atomic add.
// Block = 256 threads, 128 edges. Half h = t>>7 walks edges [64h, 64h+64);
// thread owns columns c and c+128 (c = t&127) so EVERY memory instruction is
// 64 lanes x 4B contiguous (dense sectors -- adjacent-pair layout doubled
// WRITE_SIZE via partial-sector atomics in round 5). Edge meta packed uint4.
__global__ __launch_bounds__(256)
void cfconv_gather(const float* __restrict__ X,
                   const float* __restrict__ R,
                   const unsigned int* __restrict__ tab,
                   const int* __restrict__ src,
                   const int* __restrict__ dest,
                   float* __restrict__ out,
                   float scale, int Tm2) {
    __shared__ __align__(16) uint4 meta[TEB];   // {dest, src_byteoff, tab_byteoff, frac-bits}

    const int t = threadIdx.x;
    // XCD-aware swizzle: 2048 blocks, 8 XCDs -> contiguous 256-block chunk per XCD
    const int orig = blockIdx.x;
    const int cpx = gridDim.x >> 3;
    const int wg = (orig & 7) * cpx + (orig >> 3);
    const int eb = wg * TEB;

    if (t < TEB) {
        int e = eb + t;
        int s = src[e], d = dest[e];
        float dx = R[s * 3 + 0] - R[d * 3 + 0];
        float dy = R[s * 3 + 1] - R[d * 3 + 1];
        float dz = R[s * 3 + 2] - R[d * 3 + 2];
        float D = dx * dx + dy * dy + dz * dz;
        float u = D * scale;
        int i0 = min((int)u, Tm2);
        float frac = u - (float)i0;
        uint4 mrec;
        mrec.x = (unsigned)d;
        mrec.y = (unsigned)s * (HIDDEN * 4);           // byte offset into X
        mrec.z = (unsigned)i0 * (HIDDEN * 4);          // byte offset into tab
        mrec.w = __float_as_uint(frac);
        meta[t] = mrec;
    }
    __syncthreads();

    const int rbase = (t >> 7) << 6;          // half 0 -> edges 0..63, half 1 -> 64..127
    const int c = t & 127;                    // columns c and c+128
    const char* tabc = (const char*)tab + c * 4;
    const char* Xc = (const char*)X + c * 4;

    float racc0 = 0.0f, racc1 = 0.0f;
    int dprev = __builtin_amdgcn_readfirstlane((int)meta[rbase].x);
    #pragma unroll 8
    for (int r = 0; r < 64; ++r) {
        uint4 mrec = meta[rbase + r];                       // broadcast ds_read_b128
        int d = __builtin_amdgcn_readfirstlane((int)mrec.x);
        unsigned soff = __builtin_amdgcn_readfirstlane(mrec.y);
        unsigned ioff = __builtin_amdgcn_readfirstlane(mrec.z);
        float frac = __uint_as_float(__builtin_amdgcn_readfirstlane(mrec.w));
        unsigned pair0 = *(const unsigned*)(tabc + ioff);
        unsigned pair1 = *(const unsigned*)(tabc + ioff + 128 * 4);
        float x0 = *(const float*)(Xc + soff);
        float x1 = *(const float*)(Xc + soff + 128 * 4);
        if (d != dprev) {
            float* orow = out + (size_t)dprev * HIDDEN + c;
            unsafeAtomicAdd(orow, racc0);
            unsafeAtomicAdd(orow + 128, racc1);
            racc0 = racc1 = 0.0f;
            dprev = d;
        }
        union { unsigned u; float f; } lo0, hi0, lo1, hi1;
        lo0.u = pair0 << 16; hi0.u = pair0 & 0xffff0000u;
        lo1.u = pair1 << 16; hi1.u = pair1 & 0xffff0000u;
        float m0 = fmaf(frac, hi0.f - lo0.f, lo0.f);
        float m1 = fmaf(frac, hi1.f - lo1.f, lo1.f);
        racc0 = fmaf(m0, x0, racc0);
        racc1 = fmaf(m1, x1, racc1);
    }
    float* orow = out + (size_t)dprev * HIDDEN + c;
    unsafeAtomicAdd(orow, racc0);
    unsafeAtomicAdd(orow + 128, racc1);
}

extern "C" void kernel_launch(void* const* d_in, const int* in_sizes, int n_in,
                              void* d_out, int out_size, void* d_ws, size_t ws_size,
                              hipStream_t stream) {
    const float* X  = (const float*)d_in[0];
    const float* R  = (const float*)d_in[1];
    const float* W1 = (const float*)d_in[2];
    const float* W2 = (const float*)d_in[3];
    const float* mu = (const float*)d_in[4];
    const int* src  = (const int*)d_in[5];
    const int* dest = (const int*)d_in[6];
    float* out = (float*)d_out;

    // workspace layout: W1T bf16 | W2T bf16 | pair table u32[T*256]
    unsigned short* W1T = (unsigned short*)d_ws;
    unsigned short* W2T = W1T + NB * HIDDEN;
    unsigned int*   tab = (unsigned int*)(W2T + HIDDEN * HIDDEN);

    const size_t fixed = (size_t)(NB * HIDDEN + HIDDEN * HIDDEN) * 2;
    int T = 2048;
    if (ws_size > 0) {
        while (T > 64 && fixed + (size_t)T * HIDDEN * 4 > ws_size) T >>= 1;
    }
    const float scale = (float)(T - 1) / R2MAX;
    const float invScale = R2MAX / (float)(T - 1);

    int nout4 = out_size / 4;
    int setup_blocks = (nout4 + 255) / 256;
    if (setup_blocks < (NB * HIDDEN + HIDDEN * HIDDEN + 255) / 256)
        setup_blocks = (NB * HIDDEN + HIDDEN * HIDDEN + 255) / 256;

    cfconv_setup<<<setup_blocks, 256, 0, stream>>>(W1, W2, W1T, (float4*)out, nout4);

    cfconv_build<<<T / TE, 256, 0, stream>>>(W1T, W2T, mu, (unsigned short*)tab, invScale);

    cfconv_gather<<<E_TOTAL / TEB, 256, 0, stream>>>(X, R, tab, src, dest, out,
                                                     scale, T - 2);
}

// Round 7
// 65.582 us; speedup vs baseline: 1.5174x; 1.1433x over previous
//
#include <hip/hip_runtime.h>
#include <hip/hip_bf16.h>

// Continuous-filter convolution (SchNet-style), MI355X gfx950.
// M_ij = relu(relu(rbf(D_ij)@W1)@W2) depends only on scalar D_ij in [0, R^2).
// Build a T-point bf16 pair-table of F(D) on-device (MFMA pipeline), then the
// main kernel is lerp + gather(X[src]) + run-length-reduced atomic scatter.
#define HIDDEN 256
#define NB 128
#define TB 32           // grid rows per build workgroup (512 threads, 8 waves)
#define TEB 128         // edges per gather workgroup
#define E_TOTAL 262144
#define V_TOTAL 32768
#define R2MAX 2.25f

typedef __attribute__((ext_vector_type(8))) __bf16 bf16x8;
typedef __attribute__((ext_vector_type(4))) float floatx4;

__device__ inline unsigned short f2bf(float f) {
    union { float f; unsigned u; } v; v.f = f;
    unsigned r = v.u + 0x7fffu + ((v.u >> 16) & 1u);   // RNE
    return (unsigned short)(r >> 16);
}

// Fused setup: zero the output (float4 stores) + transpose/convert weights.
//   W1T[c][k] = bf16(W1[k][c])   c<256, k<128
//   W2T[c][k] = bf16(W2[k][c])   c<256, k<256
__global__ __launch_bounds__(256)
void cfconv_setup(const float* __restrict__ W1,
                  const float* __restrict__ W2,
                  unsigned short* __restrict__ wbuf,
                  float4* __restrict__ out4, int nout4) {
    int id = blockIdx.x * 256 + threadIdx.x;
    if (id < nout4) out4[id] = make_float4(0.f, 0.f, 0.f, 0.f);
    if (id < NB * HIDDEN) {
        int c = id >> 7, k = id & (NB - 1);
        wbuf[id] = f2bf(W1[k * HIDDEN + c]);
    }
    int id2 = id - NB * HIDDEN;
    if (id2 >= 0 && id2 < HIDDEN * HIDDEN) {
        int c = id2 >> 8, k = id2 & (HIDDEN - 1);
        wbuf[NB * HIDDEN + id2] = f2bf(W2[k * HIDDEN + c]);
    }
}

// Build the F(D) table at grid points D_i = i*invScale, i in [0,T).
// tab16 is a u16 view of the u32 pair table: pair[i][c] = lo:M[i][c], hi:M[i+1][c].
// 512 threads = 8 waves in a 2(row)x4(col) grid; 32 rows per block to cut the
// single-block critical path (build runs ~1-deep per CU, latency-bound).
__global__ __launch_bounds__(512, 2)
void cfconv_build(const unsigned short* __restrict__ W1T,
                  const unsigned short* __restrict__ W2T,
                  const float* __restrict__ mu,
                  unsigned short* __restrict__ tab16,
                  float invScale) {
    __shared__ __align__(16) float mulds[NB];
    __shared__ __align__(16) unsigned short h_lds[TB * HIDDEN];   // 16 KB swizzled; h then M

    const int t = threadIdx.x;
    const int eb = blockIdx.x * TB;

    if (t < NB) mulds[t] = mu[t];
    __syncthreads();

    const int lane = t & 63;
    const int w = t >> 6;        // 0..7
    const int wr = w >> 2;       // row half 0..1 (rows 16*wr .. +16)
    const int wc = w & 3;        // col quarter 0..3 (cols 64*wc .. +64)
    const int lhi = lane >> 4;
    const int llo = lane & 15;

    // ---- GEMM1: h = relu(rbf @ W1), rbf computed in-register from grid D ----
    {
        float dm = mulds[1] - mulds[0];
        float ng = -1.0f / (dm * dm);
        float D0 = (float)(eb + 16 * wr + llo) * invScale;

        floatx4 acc[4];
        #pragma unroll
        for (int n = 0; n < 4; ++n) acc[n] = (floatx4)(0.0f);

        #pragma unroll
        for (int kc = 0; kc < 4; ++kc) {
            floatx4 mu0 = *(const floatx4*)(mulds + kc * 32 + lhi * 8);
            floatx4 mu1 = *(const floatx4*)(mulds + kc * 32 + lhi * 8 + 4);
            bf16x8 a, b[4];
            #pragma unroll
            for (int j = 0; j < 8; ++j) {
                float mv = (j < 4) ? mu0[j] : mu1[j - 4];
                float d = D0 - mv;
                a[j] = (__bf16)__expf(ng * d * d);
            }
            #pragma unroll
            for (int n = 0; n < 4; ++n) {
                int col = wc * 64 + 16 * n + llo;
                b[n] = *(const bf16x8*)(W1T + col * NB + kc * 32 + lhi * 8);
            }
            #pragma unroll
            for (int n = 0; n < 4; ++n)
                acc[n] = __builtin_amdgcn_mfma_f32_16x16x32_bf16(a, b[n], acc[n], 0, 0, 0);
        }

        char* hb = (char*)h_lds;
        #pragma unroll
        for (int n = 0; n < 4; ++n) {
            int col = wc * 64 + 16 * n + llo;
            #pragma unroll
            for (int r = 0; r < 4; ++r) {
                int row = 16 * wr + 4 * lhi + r;
                float v = fmaxf(acc[n][r], 0.0f);
                int byteoff = row * (HIDDEN * 2) + ((col * 2) ^ ((row & 7) << 4));
                *(__bf16*)(hb + byteoff) = (__bf16)v;
            }
        }
    }
    __syncthreads();

    // ---- GEMM2: M = relu(h @ W2) ----
    floatx4 acc[4];
    {
        #pragma unroll
        for (int n = 0; n < 4; ++n) acc[n] = (floatx4)(0.0f);

        const char* hb = (const char*)h_lds;
        const int arow = 16 * wr + llo;
        #pragma unroll
        for (int kc = 0; kc < 8; ++kc) {
            bf16x8 a = *(const bf16x8*)(hb + arow * (HIDDEN * 2)
                          + ((kc * 64 + 16 * lhi) ^ ((arow & 7) << 4)));
            bf16x8 b[4];
            #pragma unroll
            for (int n = 0; n < 4; ++n) {
                int col = wc * 64 + 16 * n + llo;
                b[n] = *(const bf16x8*)(W2T + col * HIDDEN + kc * 32 + lhi * 8);
            }
            #pragma unroll
            for (int n = 0; n < 4; ++n)
                acc[n] = __builtin_amdgcn_mfma_f32_16x16x32_bf16(a, b[n], acc[n], 0, 0, 0);
        }
    }
    __syncthreads();   // done reading h_lds

    // ---- store relu(M) bf16 into h_lds (swizzled) ----
    {
        char* hb = (char*)h_lds;
        #pragma unroll
        for (int n = 0; n < 4; ++n) {
            int col = wc * 64 + 16 * n + llo;
            #pragma unroll
            for (int r = 0; r < 4; ++r) {
                int row = 16 * wr + 4 * lhi + r;
                float v = fmaxf(acc[n][r], 0.0f);
                int byteoff = row * (HIDDEN * 2) + ((col * 2) ^ ((row & 7) << 4));
                *(__bf16*)(hb + byteoff) = (__bf16)v;
            }
        }
    }
    __syncthreads();

    // ---- write pair table: thread owns column c = t&255, row half rh = t>>8 ----
    {
        const char* hb = (const char*)h_lds;
        const int c = t & 255;
        const int rh = t >> 8;
        for (int r_ = 0; r_ < 16; ++r_) {
            int row = rh * 16 + r_;
            unsigned short m16 = *(const unsigned short*)(hb + row * (HIDDEN * 2)
                                   + ((2 * c) ^ ((row & 7) << 4)));
            int i = eb + row;
            tab16[((size_t)i * HIDDEN + c) * 2] = m16;               // lo of pair[i]
            if (i > 0)
                tab16[((size_t)(i - 1) * HIDDEN + c) * 2 + 1] = m16; // hi of pair[i-1]
        }
    }
}

// Main: per edge, lerp table -> * X[src] -> run-length reduced atomic add.
// Block = 256 threads, 128 edges. Wave q = t>>6 walks edge quarter
// [32q, 32q+32); thread owns 4 columns c, c+64, c+128, c+192 (c = t&63) so
// every memory instruction is 64 lanes x 4B contiguous (dense sectors).
// Explicit next-meta prefetch overlaps LDS latency with global loads.
__global__ __launch_bounds__(256)
void cfconv_gather(const float* __restrict__ X,
                   const float* __restrict__ R,
                   const unsigned int* __restrict__ tab,
                   const int* __restrict__ src,
                   const int* __restrict__ dest,
                   float* __restrict__ out,
                   float scale, int Tm2) {
    __shared__ __align__(16) uint4 meta[TEB];   // {dest, src_byteoff, tab_byteoff, frac-bits}

    const int t = threadIdx.x;
    // XCD-aware swizzle: 2048 blocks, 8 XCDs -> contiguous 256-block chunk per XCD
    const int orig = blockIdx.x;
    const int cpx = gridDim.x >> 3;
    const int wg = (orig & 7) * cpx + (orig >> 3);
    const int eb = wg * TEB;

    if (t < TEB) {
        int e = eb + t;
        int s = src[e], d = dest[e];
        float dx = R[s * 3 + 0] - R[d * 3 + 0];
        float dy = R[s * 3 + 1] - R[d * 3 + 1];
        float dz = R[s * 3 + 2] - R[d * 3 + 2];
        float D = dx * dx + dy * dy + dz * dz;
        float u = D * scale;
        int i0 = min((int)u, Tm2);
        float frac = u - (float)i0;
        uint4 mrec;
        mrec.x = (unsigned)d;
        mrec.y = (unsigned)s * (HIDDEN * 4);           // byte offset into X
        mrec.z = (unsigned)i0 * (HIDDEN * 4);          // byte offset into tab
        mrec.w = __float_as_uint(frac);
        meta[t] = mrec;
    }
    __syncthreads();

    const int q = t >> 6;                     // wave-uniform edge quarter
    const int rbase = q * 32;
    const int c = t & 63;                     // columns c + {0,64,128,192}
    const char* tabc = (const char*)tab + c * 4;
    const char* Xc = (const char*)X + c * 4;

    float a0 = 0.f, a1 = 0.f, a2 = 0.f, a3 = 0.f;
    uint4 mr = meta[rbase];
    int dprev = __builtin_amdgcn_readfirstlane((int)mr.x);
    #pragma unroll 4
    for (int r = 0; r < 32; ++r) {
        int d = __builtin_amdgcn_readfirstlane((int)mr.x);
        unsigned soff = __builtin_amdgcn_readfirstlane(mr.y);
        unsigned ioff = __builtin_amdgcn_readfirstlane(mr.z);
        float frac = __uint_as_float(__builtin_amdgcn_readfirstlane(mr.w));
        unsigned p0 = *(const unsigned*)(tabc + ioff);
        unsigned p1 = *(const unsigned*)(tabc + ioff + 256);
        unsigned p2 = *(const unsigned*)(tabc + ioff + 512);
        unsigned p3 = *(const unsigned*)(tabc + ioff + 768);
        float x0 = *(const float*)(Xc + soff);
        float x1 = *(const float*)(Xc + soff + 256);
        float x2 = *(const float*)(Xc + soff + 512);
        float x3 = *(const float*)(Xc + soff + 768);
        if (r + 1 < 32) mr = meta[rbase + r + 1];    // prefetch next meta
        if (d != dprev) {
            float* orow = out + (size_t)dprev * HIDDEN + c;
            unsafeAtomicAdd(orow, a0);
            unsafeAtomicAdd(orow + 64, a1);
            unsafeAtomicAdd(orow + 128, a2);
            unsafeAtomicAdd(orow + 192, a3);
            a0 = a1 = a2 = a3 = 0.f;
            dprev = d;
        }
        union { unsigned u; float f; } lo, hi;
        lo.u = p0 << 16; hi.u = p0 & 0xffff0000u;
        a0 = fmaf(fmaf(frac, hi.f - lo.f, lo.f), x0, a0);
        lo.u = p1 << 16; hi.u = p1 & 0xffff0000u;
        a1 = fmaf(fmaf(frac, hi.f - lo.f, lo.f), x1, a1);
        lo.u = p2 << 16; hi.u = p2 & 0xffff0000u;
        a2 = fmaf(fmaf(frac, hi.f - lo.f, lo.f), x2, a2);
        lo.u = p3 << 16; hi.u = p3 & 0xffff0000u;
        a3 = fmaf(fmaf(frac, hi.f - lo.f, lo.f), x3, a3);
    }
    float* orow = out + (size_t)dprev * HIDDEN + c;
    unsafeAtomicAdd(orow, a0);
    unsafeAtomicAdd(orow + 64, a1);
    unsafeAtomicAdd(orow + 128, a2);
    unsafeAtomicAdd(orow + 192, a3);
}

extern "C" void kernel_launch(void* const* d_in, const int* in_sizes, int n_in,
                              void* d_out, int out_size, void* d_ws, size_t ws_size,
                              hipStream_t stream) {
    const float* X  = (const float*)d_in[0];
    const float* R  = (const float*)d_in[1];
    const float* W1 = (const float*)d_in[2];
    const float* W2 = (const float*)d_in[3];
    const float* mu = (const float*)d_in[4];
    const int* src  = (const int*)d_in[5];
    const int* dest = (const int*)d_in[6];
    float* out = (float*)d_out;

    // workspace layout: W1T bf16 | W2T bf16 | pair table u32[T*256]
    unsigned short* W1T = (unsigned short*)d_ws;
    unsigned short* W2T = W1T + NB * HIDDEN;
    unsigned int*   tab = (unsigned int*)(W2T + HIDDEN * HIDDEN);

    const size_t fixed = (size_t)(NB * HIDDEN + HIDDEN * HIDDEN) * 2;
    int T = 2048;
    if (ws_size > 0) {
        while (T > 64 && fixed + (size_t)T * HIDDEN * 4 > ws_size) T >>= 1;
    }
    const float scale = (float)(T - 1) / R2MAX;
    const float invScale = R2MAX / (float)(T - 1);

    int nout4 = out_size / 4;
    int setup_blocks = (nout4 + 255) / 256;
    if (setup_blocks < (NB * HIDDEN + HIDDEN * HIDDEN + 255) / 256)
        setup_blocks = (NB * HIDDEN + HIDDEN * HIDDEN + 255) / 256;

    cfconv_setup<<<setup_blocks, 256, 0, stream>>>(W1, W2, W1T, (float4*)out, nout4);

    cfconv_build<<<T / TB, 512, 0, stream>>>(W1T, W2T, mu, (unsigned short*)tab, invScale);

    cfconv_gather<<<E_TOTAL / TEB, 256, 0, stream>>>(X, R, tab, src, dest, out,
                                                     scale, T - 2);
}

// Round 8
// 62.950 us; speedup vs baseline: 1.5808x; 1.0418x over previous
//
#include <hip/hip_runtime.h>
#include <hip/hip_bf16.h>

// Continuous-filter convolution (SchNet-style), MI355X gfx950.
// M_ij = relu(relu(rbf(D_ij)@W1)@W2) depends only on scalar D_ij in [0, R^2).
// Build a T=4096-point bf16 nearest-neighbor table of F(D) on-device (MFMA
// pipeline), then the main kernel is table-lookup + gather(X[src]) +
// run-length-reduced atomic scatter with a hand-rotated 2-deep load pipeline.
#define HIDDEN 256
#define NB 128
#define TB 32           // grid rows per build workgroup (512 threads, 8 waves)
#define TEB 128         // edges per gather workgroup
#define E_TOTAL 262144
#define V_TOTAL 32768
#define R2MAX 2.25f

typedef __attribute__((ext_vector_type(8))) __bf16 bf16x8;
typedef __attribute__((ext_vector_type(4))) float floatx4;

__device__ inline unsigned short f2bf(float f) {
    union { float f; unsigned u; } v; v.f = f;
    unsigned r = v.u + 0x7fffu + ((v.u >> 16) & 1u);   // RNE
    return (unsigned short)(r >> 16);
}

// Setup: transpose/convert weights only (zeroing rides in cfconv_build).
//   W1T[c][k] = bf16(W1[k][c])   c<256, k<128
//   W2T[c][k] = bf16(W2[k][c])   c<256, k<256
__global__ __launch_bounds__(256)
void cfconv_setup(const float* __restrict__ W1,
                  const float* __restrict__ W2,
                  unsigned short* __restrict__ wbuf) {
    int id = blockIdx.x * 256 + threadIdx.x;
    if (id < NB * HIDDEN) {
        int c = id >> 7, k = id & (NB - 1);
        wbuf[id] = f2bf(W1[k * HIDDEN + c]);
    }
    int id2 = id - NB * HIDDEN;
    if (id2 >= 0 && id2 < HIDDEN * HIDDEN) {
        int c = id2 >> 8, k = id2 & (HIDDEN - 1);
        wbuf[NB * HIDDEN + id2] = f2bf(W2[k * HIDDEN + c]);
    }
}

// Build the F(D) table at grid points D_i = i*invScale, i in [0,T).
// tab16[i*256+c] = bf16(F_c(D_i)). Blocks >= nTabBlocks zero the output
// instead (BW-bound work overlapping the latency-bound table blocks).
__global__ __launch_bounds__(512, 2)
void cfconv_build(const unsigned short* __restrict__ W1T,
                  const unsigned short* __restrict__ W2T,
                  const float* __restrict__ mu,
                  unsigned short* __restrict__ tab16,
                  float invScale, int nTabBlocks,
                  float4* __restrict__ out4, int nout4) {
    __shared__ __align__(16) float mulds[NB];
    __shared__ __align__(16) unsigned short h_lds[TB * HIDDEN];   // 16 KB swizzled; h then M

    const int t = threadIdx.x;

    if (blockIdx.x >= nTabBlocks) {        // zero-rider block
        int id = (blockIdx.x - nTabBlocks) * 512 + t;
        int stride = (gridDim.x - nTabBlocks) * 512;
        for (int i = id; i < nout4; i += stride)
            out4[i] = make_float4(0.f, 0.f, 0.f, 0.f);
        return;
    }

    const int eb = blockIdx.x * TB;

    if (t < NB) mulds[t] = mu[t];
    __syncthreads();

    const int lane = t & 63;
    const int w = t >> 6;        // 0..7
    const int wr = w >> 2;       // row half 0..1 (rows 16*wr .. +16)
    const int wc = w & 3;        // col quarter 0..3 (cols 64*wc .. +64)
    const int lhi = lane >> 4;
    const int llo = lane & 15;

    // ---- GEMM1: h = relu(rbf @ W1), rbf computed in-register from grid D ----
    {
        float dm = mulds[1] - mulds[0];
        float ng = -1.0f / (dm * dm);
        float D0 = (float)(eb + 16 * wr + llo) * invScale;

        floatx4 acc[4];
        #pragma unroll
        for (int n = 0; n < 4; ++n) acc[n] = (floatx4)(0.0f);

        #pragma unroll
        for (int kc = 0; kc < 4; ++kc) {
            floatx4 mu0 = *(const floatx4*)(mulds + kc * 32 + lhi * 8);
            floatx4 mu1 = *(const floatx4*)(mulds + kc * 32 + lhi * 8 + 4);
            bf16x8 a, b[4];
            #pragma unroll
            for (int j = 0; j < 8; ++j) {
                float mv = (j < 4) ? mu0[j] : mu1[j - 4];
                float d = D0 - mv;
                a[j] = (__bf16)__expf(ng * d * d);
            }
            #pragma unroll
            for (int n = 0; n < 4; ++n) {
                int col = wc * 64 + 16 * n + llo;
                b[n] = *(const bf16x8*)(W1T + col * NB + kc * 32 + lhi * 8);
            }
            #pragma unroll
            for (int n = 0; n < 4; ++n)
                acc[n] = __builtin_amdgcn_mfma_f32_16x16x32_bf16(a, b[n], acc[n], 0, 0, 0);
        }

        char* hb = (char*)h_lds;
        #pragma unroll
        for (int n = 0; n < 4; ++n) {
            int col = wc * 64 + 16 * n + llo;
            #pragma unroll
            for (int r = 0; r < 4; ++r) {
                int row = 16 * wr + 4 * lhi + r;
                float v = fmaxf(acc[n][r], 0.0f);
                int byteoff = row * (HIDDEN * 2) + ((col * 2) ^ ((row & 7) << 4));
                *(__bf16*)(hb + byteoff) = (__bf16)v;
            }
        }
    }
    __syncthreads();

    // ---- GEMM2: M = relu(h @ W2) ----
    floatx4 acc[4];
    {
        #pragma unroll
        for (int n = 0; n < 4; ++n) acc[n] = (floatx4)(0.0f);

        const char* hb = (const char*)h_lds;
        const int arow = 16 * wr + llo;
        #pragma unroll
        for (int kc = 0; kc < 8; ++kc) {
            bf16x8 a = *(const bf16x8*)(hb + arow * (HIDDEN * 2)
                          + ((kc * 64 + 16 * lhi) ^ ((arow & 7) << 4)));
            bf16x8 b[4];
            #pragma unroll
            for (int n = 0; n < 4; ++n) {
                int col = wc * 64 + 16 * n + llo;
                b[n] = *(const bf16x8*)(W2T + col * HIDDEN + kc * 32 + lhi * 8);
            }
            #pragma unroll
            for (int n = 0; n < 4; ++n)
                acc[n] = __builtin_amdgcn_mfma_f32_16x16x32_bf16(a, b[n], acc[n], 0, 0, 0);
        }
    }
    __syncthreads();   // done reading h_lds

    // ---- store relu(M) bf16 into h_lds (swizzled) ----
    {
        char* hb = (char*)h_lds;
        #pragma unroll
        for (int n = 0; n < 4; ++n) {
            int col = wc * 64 + 16 * n + llo;
            #pragma unroll
            for (int r = 0; r < 4; ++r) {
                int row = 16 * wr + 4 * lhi + r;
                float v = fmaxf(acc[n][r], 0.0f);
                int byteoff = row * (HIDDEN * 2) + ((col * 2) ^ ((row & 7) << 4));
                *(__bf16*)(hb + byteoff) = (__bf16)v;
            }
        }
    }
    __syncthreads();

    // ---- write table: thread owns column c = t&255, row half rh = t>>8 ----
    {
        const char* hb = (const char*)h_lds;
        const int c = t & 255;
        const int rh = t >> 8;
        for (int r_ = 0; r_ < 16; ++r_) {
            int row = rh * 16 + r_;
            unsigned short m16 = *(const unsigned short*)(hb + row * (HIDDEN * 2)
                                   + ((2 * c) ^ ((row & 7) << 4)));
            tab16[(size_t)(eb + row) * HIDDEN + c] = m16;
        }
    }
}

// Main: per edge, NN table row -> * X[src] -> run-length reduced atomic add.
// Block = 256 threads, 128 edges. Wave q = t>>6 walks edge quarter
// [32q, 32q+32); thread owns 4 columns c, c+64, c+128, c+192 (c = t&63) so
// every memory instruction is 64 lanes dense-contiguous. Hand-rotated 2-deep
// A/B load pipeline keeps the next edge's 8 loads in flight across the
// run-flush branches (per-BB scheduler won't do it for us).
__global__ __launch_bounds__(256)
void cfconv_gather(const float* __restrict__ X,
                   const float* __restrict__ R,
                   const unsigned short* __restrict__ tab,
                   const int* __restrict__ src,
                   const int* __restrict__ dest,
                   float* __restrict__ out,
                   float scale, int Tm1) {
    __shared__ __align__(16) uint4 meta[TEB];   // {dest, X byteoff, tab byteoff, 0}

    const int t = threadIdx.x;
    // XCD-aware swizzle: 2048 blocks, 8 XCDs -> contiguous 256-block chunk per XCD
    const int orig = blockIdx.x;
    const int cpx = gridDim.x >> 3;
    const int wg = (orig & 7) * cpx + (orig >> 3);
    const int eb = wg * TEB;

    if (t < TEB) {
        int e = eb + t;
        int s = src[e], d = dest[e];
        float dx = R[s * 3 + 0] - R[d * 3 + 0];
        float dy = R[s * 3 + 1] - R[d * 3 + 1];
        float dz = R[s * 3 + 2] - R[d * 3 + 2];
        float D = dx * dx + dy * dy + dz * dz;
        int i0 = min((int)(D * scale + 0.5f), Tm1);
        uint4 mrec;
        mrec.x = (unsigned)d;
        mrec.y = (unsigned)s * (HIDDEN * 4);           // byte offset into X (f32 row)
        mrec.z = (unsigned)i0 * (HIDDEN * 2);          // byte offset into tab (bf16 row)
        mrec.w = 0u;
        meta[t] = mrec;
    }
    __syncthreads();

    const int q = t >> 6;                     // wave-uniform edge quarter
    const int rbase = q * 32;
    const int c = t & 63;                     // columns c + {0,64,128,192}
    const char* tabc = (const char*)tab + c * 2;
    const char* Xc = (const char*)X + c * 4;

    float a0 = 0.f, a1 = 0.f, a2 = 0.f, a3 = 0.f;

#define FLUSH(dp) { \
        float* orow = out + (size_t)(dp) * HIDDEN + c; \
        unsafeAtomicAdd(orow, a0); \
        unsafeAtomicAdd(orow + 64, a1); \
        unsafeAtomicAdd(orow + 128, a2); \
        unsafeAtomicAdd(orow + 192, a3); \
        a0 = a1 = a2 = a3 = 0.f; }

#define ACC(p0, p1, p2, p3, x0, x1, x2, x3) { \
        union { unsigned u; float f; } mm; \
        mm.u = ((unsigned)(p0)) << 16; a0 = fmaf(mm.f, (x0), a0); \
        mm.u = ((unsigned)(p1)) << 16; a1 = fmaf(mm.f, (x1), a1); \
        mm.u = ((unsigned)(p2)) << 16; a2 = fmaf(mm.f, (x2), a2); \
        mm.u = ((unsigned)(p3)) << 16; a3 = fmaf(mm.f, (x3), a3); }

    // ---- prologue: meta+loads for edge 0 (A), meta for edge 1 (B) ----
    uint4 mA = meta[rbase];
    int dA = __builtin_amdgcn_readfirstlane((int)mA.x);
    unsigned soA = __builtin_amdgcn_readfirstlane(mA.y);
    unsigned ioA = __builtin_amdgcn_readfirstlane(mA.z);
    int dprev = dA;
    unsigned short pa0 = *(const unsigned short*)(tabc + ioA);
    unsigned short pa1 = *(const unsigned short*)(tabc + ioA + 128);
    unsigned short pa2 = *(const unsigned short*)(tabc + ioA + 256);
    unsigned short pa3 = *(const unsigned short*)(tabc + ioA + 384);
    float xa0 = *(const float*)(Xc + soA);
    float xa1 = *(const float*)(Xc + soA + 256);
    float xa2 = *(const float*)(Xc + soA + 512);
    float xa3 = *(const float*)(Xc + soA + 768);
    uint4 mB = meta[rbase + 1];
    int dB = __builtin_amdgcn_readfirstlane((int)mB.x);
    unsigned soB = __builtin_amdgcn_readfirstlane(mB.y);
    unsigned ioB = __builtin_amdgcn_readfirstlane(mB.z);

    for (int rr = 0; rr < 16; ++rr) {
        // ---- even edge 2rr: A loads ready-ish ----
        if (dA != dprev) { FLUSH(dprev); dprev = dA; }
        // issue B loads (edge 2rr+1)
        unsigned short pb0 = *(const unsigned short*)(tabc + ioB);
        unsigned short pb1 = *(const unsigned short*)(tabc + ioB + 128);
        unsigned short pb2 = *(const unsigned short*)(tabc + ioB + 256);
        unsigned short pb3 = *(const unsigned short*)(tabc + ioB + 384);
        float xb0 = *(const float*)(Xc + soB);
        float xb1 = *(const float*)(Xc + soB + 256);
        float xb2 = *(const float*)(Xc + soB + 512);
        float xb3 = *(const float*)(Xc + soB + 768);
        // prefetch meta for edge 2rr+2 into A slot (wraps harmlessly at tail)
        {
            uint4 m = meta[rbase + ((2 * rr + 2) & 31)];
            dA = __builtin_amdgcn_readfirstlane((int)m.x);
            soA = __builtin_amdgcn_readfirstlane(m.y);
            ioA = __builtin_amdgcn_readfirstlane(m.z);
        }
        ACC(pa0, pa1, pa2, pa3, xa0, xa1, xa2, xa3);

        // ---- odd edge 2rr+1: B loads ----
        if (dB != dprev) { FLUSH(dprev); dprev = dB; }
        // issue A loads (edge 2rr+2; tail issues wrapped/unused loads)
        pa0 = *(const unsigned short*)(tabc + ioA);
        pa1 = *(const unsigned short*)(tabc + ioA + 128);
        pa2 = *(const unsigned short*)(tabc + ioA + 256);
        pa3 = *(const unsigned short*)(tabc + ioA + 384);
        xa0 = *(const float*)(Xc + soA);
        xa1 = *(const float*)(Xc + soA + 256);
        xa2 = *(const float*)(Xc + soA + 512);
        xa3 = *(const float*)(Xc + soA + 768);
        // prefetch meta for edge 2rr+3 into B slot
        {
            uint4 m = meta[rbase + ((2 * rr + 3) & 31)];
            dB = __builtin_amdgcn_readfirstlane((int)m.x);
            soB = __builtin_amdgcn_readfirstlane(m.y);
            ioB = __builtin_amdgcn_readfirstlane(m.z);
        }
        ACC(pb0, pb1, pb2, pb3, xb0, xb1, xb2, xb3);
    }
    FLUSH(dprev);
#undef FLUSH
#undef ACC
}

extern "C" void kernel_launch(void* const* d_in, const int* in_sizes, int n_in,
                              void* d_out, int out_size, void* d_ws, size_t ws_size,
                              hipStream_t stream) {
    const float* X  = (const float*)d_in[0];
    const float* R  = (const float*)d_in[1];
    const float* W1 = (const float*)d_in[2];
    const float* W2 = (const float*)d_in[3];
    const float* mu = (const float*)d_in[4];
    const int* src  = (const int*)d_in[5];
    const int* dest = (const int*)d_in[6];
    float* out = (float*)d_out;

    // workspace layout: W1T bf16 | W2T bf16 | NN table bf16[T*256]
    unsigned short* W1T = (unsigned short*)d_ws;
    unsigned short* W2T = W1T + NB * HIDDEN;
    unsigned short* tab = W2T + HIDDEN * HIDDEN;

    const size_t fixed = (size_t)(NB * HIDDEN + HIDDEN * HIDDEN) * 2;
    int T = 4096;
    if (ws_size > 0) {
        while (T > 64 && fixed + (size_t)T * HIDDEN * 2 > ws_size) T >>= 1;
    }
    const float scale = (float)(T - 1) / R2MAX;
    const float invScale = R2MAX / (float)(T - 1);

    int nout4 = out_size / 4;
    int nTabBlocks = T / TB;
    int zeroBlocks = 1024;

    cfconv_setup<<<(NB * HIDDEN + HIDDEN * HIDDEN + 255) / 256, 256, 0, stream>>>(W1, W2, W1T);

    cfconv_build<<<nTabBlocks + zeroBlocks, 512, 0, stream>>>(
        W1T, W2T, mu, tab, invScale, nTabBlocks, (float4*)out, nout4);

    cfconv_gather<<<E_TOTAL / TEB, 256, 0, stream>>>(X, R, tab, src, dest, out,
                                                     scale, T - 1);
}

// Round 9
// 62.726 us; speedup vs baseline: 1.5865x; 1.0036x over previous
//
#include <hip/hip_runtime.h>
#include <hip/hip_bf16.h>

// Continuous-filter convolution (SchNet-style), MI355X gfx950.
// M_ij = relu(relu(rbf(D_ij)@W1)@W2) depends only on scalar D_ij in [0, R^2).
// Build a T=4096-point bf16 nearest-neighbor table of F(D) on-device (MFMA
// pipeline), then the main kernel is table-lookup + gather(X[src]) +
// run-length-reduced atomic scatter with a 4-deep rotated load pipeline.
// Table rows are PAIR-INTERLEAVED: u16 slot ((g>>1)<<7 | r<<1 | (g&1)) holds
// col 64g+r, so lane r reads cols (r, r+64) as one dword and (r+128, r+192)
// as another -> 2 dense 256B tab loads per edge instead of 4 half-dense.
#define HIDDEN 256
#define NB 128
#define TB 32           // grid rows per build workgroup (512 threads, 8 waves)
#define TEB 128         // edges per gather workgroup
#define E_TOTAL 262144
#define V_TOTAL 32768
#define R2MAX 2.25f

typedef __attribute__((ext_vector_type(8))) __bf16 bf16x8;
typedef __attribute__((ext_vector_type(4))) float floatx4;

__device__ inline unsigned short f2bf(float f) {
    union { float f; unsigned u; } v; v.f = f;
    unsigned r = v.u + 0x7fffu + ((v.u >> 16) & 1u);   // RNE
    return (unsigned short)(r >> 16);
}

// Setup: transpose/convert weights only (zeroing rides in cfconv_build).
__global__ __launch_bounds__(256)
void cfconv_setup(const float* __restrict__ W1,
                  const float* __restrict__ W2,
                  unsigned short* __restrict__ wbuf) {
    int id = blockIdx.x * 256 + threadIdx.x;
    if (id < NB * HIDDEN) {
        int c = id >> 7, k = id & (NB - 1);
        wbuf[id] = f2bf(W1[k * HIDDEN + c]);
    }
    int id2 = id - NB * HIDDEN;
    if (id2 >= 0 && id2 < HIDDEN * HIDDEN) {
        int c = id2 >> 8, k = id2 & (HIDDEN - 1);
        wbuf[NB * HIDDEN + id2] = f2bf(W2[k * HIDDEN + c]);
    }
}

// Build the F(D) table at grid points D_i = i*invScale, i in [0,T).
// Blocks >= nTabBlocks zero the output instead (BW-bound rider work).
__global__ __launch_bounds__(512, 2)
void cfconv_build(const unsigned short* __restrict__ W1T,
                  const unsigned short* __restrict__ W2T,
                  const float* __restrict__ mu,
                  unsigned short* __restrict__ tab16,
                  float invScale, int nTabBlocks,
                  float4* __restrict__ out4, int nout4) {
    __shared__ __align__(16) float mulds[NB];
    __shared__ __align__(16) unsigned short h_lds[TB * HIDDEN];   // 16 KB swizzled; h then M

    const int t = threadIdx.x;

    if (blockIdx.x >= nTabBlocks) {        // zero-rider block
        int id = (blockIdx.x - nTabBlocks) * 512 + t;
        int stride = (gridDim.x - nTabBlocks) * 512;
        for (int i = id; i < nout4; i += stride)
            out4[i] = make_float4(0.f, 0.f, 0.f, 0.f);
        return;
    }

    const int eb = blockIdx.x * TB;

    if (t < NB) mulds[t] = mu[t];
    __syncthreads();

    const int lane = t & 63;
    const int w = t >> 6;        // 0..7
    const int wr = w >> 2;       // row half 0..1 (rows 16*wr .. +16)
    const int wc = w & 3;        // col quarter 0..3 (cols 64*wc .. +64)
    const int lhi = lane >> 4;
    const int llo = lane & 15;

    // ---- GEMM1: h = relu(rbf @ W1), rbf computed in-register from grid D ----
    {
        float dm = mulds[1] - mulds[0];
        float ng = -1.0f / (dm * dm);
        float D0 = (float)(eb + 16 * wr + llo) * invScale;

        floatx4 acc[4];
        #pragma unroll
        for (int n = 0; n < 4; ++n) acc[n] = (floatx4)(0.0f);

        #pragma unroll
        for (int kc = 0; kc < 4; ++kc) {
            floatx4 mu0 = *(const floatx4*)(mulds + kc * 32 + lhi * 8);
            floatx4 mu1 = *(const floatx4*)(mulds + kc * 32 + lhi * 8 + 4);
            bf16x8 a, b[4];
            #pragma unroll
            for (int j = 0; j < 8; ++j) {
                float mv = (j < 4) ? mu0[j] : mu1[j - 4];
                float d = D0 - mv;
                a[j] = (__bf16)__expf(ng * d * d);
            }
            #pragma unroll
            for (int n = 0; n < 4; ++n) {
                int col = wc * 64 + 16 * n + llo;
                b[n] = *(const bf16x8*)(W1T + col * NB + kc * 32 + lhi * 8);
            }
            #pragma unroll
            for (int n = 0; n < 4; ++n)
                acc[n] = __builtin_amdgcn_mfma_f32_16x16x32_bf16(a, b[n], acc[n], 0, 0, 0);
        }

        char* hb = (char*)h_lds;
        #pragma unroll
        for (int n = 0; n < 4; ++n) {
            int col = wc * 64 + 16 * n + llo;
            #pragma unroll
            for (int r = 0; r < 4; ++r) {
                int row = 16 * wr + 4 * lhi + r;
                float v = fmaxf(acc[n][r], 0.0f);
                int byteoff = row * (HIDDEN * 2) + ((col * 2) ^ ((row & 7) << 4));
                *(__bf16*)(hb + byteoff) = (__bf16)v;
            }
        }
    }
    __syncthreads();

    // ---- GEMM2: M = relu(h @ W2) ----
    floatx4 acc[4];
    {
        #pragma unroll
        for (int n = 0; n < 4; ++n) acc[n] = (floatx4)(0.0f);

        const char* hb = (const char*)h_lds;
        const int arow = 16 * wr + llo;
        #pragma unroll
        for (int kc = 0; kc < 8; ++kc) {
            bf16x8 a = *(const bf16x8*)(hb + arow * (HIDDEN * 2)
                          + ((kc * 64 + 16 * lhi) ^ ((arow & 7) << 4)));
            bf16x8 b[4];
            #pragma unroll
            for (int n = 0; n < 4; ++n) {
                int col = wc * 64 + 16 * n + llo;
                b[n] = *(const bf16x8*)(W2T + col * HIDDEN + kc * 32 + lhi * 8);
            }
            #pragma unroll
            for (int n = 0; n < 4; ++n)
                acc[n] = __builtin_amdgcn_mfma_f32_16x16x32_bf16(a, b[n], acc[n], 0, 0, 0);
        }
    }
    __syncthreads();   // done reading h_lds

    // ---- store relu(M) bf16 into h_lds (swizzled) ----
    {
        char* hb = (char*)h_lds;
        #pragma unroll
        for (int n = 0; n < 4; ++n) {
            int col = wc * 64 + 16 * n + llo;
            #pragma unroll
            for (int r = 0; r < 4; ++r) {
                int row = 16 * wr + 4 * lhi + r;
                float v = fmaxf(acc[n][r], 0.0f);
                int byteoff = row * (HIDDEN * 2) + ((col * 2) ^ ((row & 7) << 4));
                *(__bf16*)(hb + byteoff) = (__bf16)v;
            }
        }
    }
    __syncthreads();

    // ---- write table (pair-interleaved): col 64g+r -> u16 slot
    //      ((g>>1)<<7) | (r<<1) | (g&1), per row ----
    {
        const char* hb = (const char*)h_lds;
        const int c = t & 255;
        const int rh = t >> 8;
        const int slot = (((c >> 7) & 1) << 7) | ((c & 63) << 1) | ((c >> 6) & 1);
        for (int r_ = 0; r_ < 16; ++r_) {
            int row = rh * 16 + r_;
            unsigned short m16 = *(const unsigned short*)(hb + row * (HIDDEN * 2)
                                   + ((2 * c) ^ ((row & 7) << 4)));
            tab16[(size_t)(eb + row) * HIDDEN + slot] = m16;
        }
    }
}

// Main: per edge, NN table row -> * X[src] -> run-length reduced atomic add.
// Block = 256 threads, 128 edges. Wave q = t>>6 walks edge quarter
// [32q, 32q+32); thread owns 4 columns c, c+64, c+128, c+192 (c = t&63).
// 4-deep rotated A/B/C/D load pipeline: at each consume, 3 other stages'
// loads (18 vmem) are in flight -> L2 latency fully covered across the
// run-flush branches. All loads/atomics are 64-lane dense.
__global__ __launch_bounds__(256)
void cfconv_gather(const float* __restrict__ X,
                   const float* __restrict__ R,
                   const unsigned int* __restrict__ tab,
                   const int* __restrict__ src,
                   const int* __restrict__ dest,
                   float* __restrict__ out,
                   float scale, int Tm1) {
    __shared__ __align__(16) uint4 meta[TEB];   // {dest, X byteoff, tab byteoff, 0}

    const int t = threadIdx.x;
    // XCD-aware swizzle: 2048 blocks, 8 XCDs -> contiguous 256-block chunk per XCD
    const int orig = blockIdx.x;
    const int cpx = gridDim.x >> 3;
    const int wg = (orig & 7) * cpx + (orig >> 3);
    const int eb = wg * TEB;

    if (t < TEB) {
        int e = eb + t;
        int s = src[e], d = dest[e];
        float dx = R[s * 3 + 0] - R[d * 3 + 0];
        float dy = R[s * 3 + 1] - R[d * 3 + 1];
        float dz = R[s * 3 + 2] - R[d * 3 + 2];
        float D = dx * dx + dy * dy + dz * dz;
        int i0 = min((int)(D * scale + 0.5f), Tm1);
        uint4 mrec;
        mrec.x = (unsigned)d;
        mrec.y = (unsigned)s * (HIDDEN * 4);           // byte offset into X (f32 row)
        mrec.z = (unsigned)i0 * (HIDDEN * 2);          // byte offset into tab row
        mrec.w = 0u;
        meta[t] = mrec;
    }
    __syncthreads();

    const int q = t >> 6;                     // wave-uniform edge quarter
    const int rbase = q * 32;
    const int c = t & 63;                     // columns c + {0,64,128,192}
    const char* tabc = (const char*)tab + c * 4;   // pair-interleaved row
    const char* Xc = (const char*)X + c * 4;

    float a0 = 0.f, a1 = 0.f, a2 = 0.f, a3 = 0.f;

#define RF(x) __builtin_amdgcn_readfirstlane((int)(x))

#define FLUSH(dp) { \
        float* orow = out + (size_t)(dp) * HIDDEN + c; \
        unsafeAtomicAdd(orow, a0); \
        unsafeAtomicAdd(orow + 64, a1); \
        unsafeAtomicAdd(orow + 128, a2); \
        unsafeAtomicAdd(orow + 192, a3); \
        a0 = a1 = a2 = a3 = 0.f; }

#define DECL_STAGE(S) \
    int d##S; unsigned so##S, io##S; \
    unsigned q##S##0, q##S##1; \
    float x##S##0, x##S##1, x##S##2, x##S##3;

#define MET(S, idx) { \
    uint4 m_ = meta[rbase + ((idx) & 31)]; \
    d##S = RF(m_.x); so##S = (unsigned)RF(m_.y); io##S = (unsigned)RF(m_.z); }

#define LD(S) \
    q##S##0 = *(const unsigned*)(tabc + io##S); \
    q##S##1 = *(const unsigned*)(tabc + io##S + 256); \
    x##S##0 = *(const float*)(Xc + so##S); \
    x##S##1 = *(const float*)(Xc + so##S + 256); \
    x##S##2 = *(const float*)(Xc + so##S + 512); \
    x##S##3 = *(const float*)(Xc + so##S + 768);

#define CONSUME(S, nextidx) { \
    if (d##S != dprev) { FLUSH(dprev); dprev = d##S; } \
    union { unsigned u; float f; } mm_; \
    mm_.u = q##S##0 << 16;           a0 = fmaf(mm_.f, x##S##0, a0); \
    mm_.u = q##S##0 & 0xffff0000u;   a1 = fmaf(mm_.f, x##S##1, a1); \
    mm_.u = q##S##1 << 16;           a2 = fmaf(mm_.f, x##S##2, a2); \
    mm_.u = q##S##1 & 0xffff0000u;   a3 = fmaf(mm_.f, x##S##3, a3); \
    MET(S, nextidx); \
    LD(S); }

    DECL_STAGE(A) DECL_STAGE(B) DECL_STAGE(C) DECL_STAGE(D)

    MET(A, 0) LD(A)
    MET(B, 1) LD(B)
    MET(C, 2) LD(C)
    MET(D, 3) LD(D)
    int dprev = dA;

    #pragma unroll 2
    for (int rr = 0; rr < 8; ++rr) {
        int nb = rr * 4 + 4;       // next-group base (wraps harmlessly at tail)
        CONSUME(A, nb)
        CONSUME(B, nb + 1)
        CONSUME(C, nb + 2)
        CONSUME(D, nb + 3)
    }
    FLUSH(dprev);

#undef RF
#undef FLUSH
#undef DECL_STAGE
#undef MET
#undef LD
#undef CONSUME
}

extern "C" void kernel_launch(void* const* d_in, const int* in_sizes, int n_in,
                              void* d_out, int out_size, void* d_ws, size_t ws_size,
                              hipStream_t stream) {
    const float* X  = (const float*)d_in[0];
    const float* R  = (const float*)d_in[1];
    const float* W1 = (const float*)d_in[2];
    const float* W2 = (const float*)d_in[3];
    const float* mu = (const float*)d_in[4];
    const int* src  = (const int*)d_in[5];
    const int* dest = (const int*)d_in[6];
    float* out = (float*)d_out;

    // workspace layout: W1T bf16 | W2T bf16 | NN table bf16[T*256]
    unsigned short* W1T = (unsigned short*)d_ws;
    unsigned short* W2T = W1T + NB * HIDDEN;
    unsigned short* tab = W2T + HIDDEN * HIDDEN;

    const size_t fixed = (size_t)(NB * HIDDEN + HIDDEN * HIDDEN) * 2;
    int T = 4096;
    if (ws_size > 0) {
        while (T > 64 && fixed + (size_t)T * HIDDEN * 2 > ws_size) T >>= 1;
    }
    const float scale = (float)(T - 1) / R2MAX;
    const float invScale = R2MAX / (float)(T - 1);

    int nout4 = out_size / 4;
    int nTabBlocks = T / TB;
    int zeroBlocks = 1024;

    cfconv_setup<<<(NB * HIDDEN + HIDDEN * HIDDEN + 255) / 256, 256, 0, stream>>>(W1, W2, W1T);

    cfconv_build<<<nTabBlocks + zeroBlocks, 512, 0, stream>>>(
        W1T, W2T, mu, tab, invScale, nTabBlocks, (float4*)out, nout4);

    cfconv_gather<<<E_TOTAL / TEB, 256, 0, stream>>>(X, R, (const unsigned int*)tab,
                                                     src, dest, out, scale, T - 1);
}

// Round 10
// 55.117 us; speedup vs baseline: 1.8055x; 1.1381x over previous
//
#include <hip/hip_runtime.h>
#include <hip/hip_bf16.h>

// Continuous-filter convolution (SchNet-style), MI355X gfx950.
// M_ij = relu(relu(rbf(D_ij)@W1)@W2) depends only on scalar D_ij in [0, R^2).
// Kernel 1 (build): MFMA table build (weights transposed in-register from f32
//   globals) + rider blocks that zero `out` and convert X to quad-interleaved
//   bf16. Kernel 2 (gather): per edge 2 dense loads (tab+Xb dwordx2) ->
//   4 fma -> run-length-reduced atomic scatter, 4-deep rotated pipeline.
// Quad-interleave: row slot s (0..63) holds cols {s, s+64, s+128, s+192} as
// 4 bf16 in 8 bytes -> lane s reads all 4 of its columns with ONE dwordx2.
#define HIDDEN 256
#define NB 128
#define TB 32           // grid rows per build workgroup (512 threads, 8 waves)
#define TEB 128         // edges per gather workgroup
#define E_TOTAL 262144
#define V_TOTAL 32768
#define R2MAX 2.25f

typedef __attribute__((ext_vector_type(8))) __bf16 bf16x8;
typedef __attribute__((ext_vector_type(4))) float floatx4;

__device__ inline unsigned short f2bf(float f) {
    union { float f; unsigned u; } v; v.f = f;
    unsigned r = v.u + 0x7fffu + ((v.u >> 16) & 1u);   // RNE
    return (unsigned short)(r >> 16);
}

// Build the F(D) table at grid points D_i = i*invScale, i in [0,T), writing
// quad-interleaved bf16 rows. Blocks >= nTabBlocks are riders: zero `out`
// (dense float4) and convert X (f32) -> Xb (bf16 quad-interleaved, dense).
__global__ __launch_bounds__(512, 2)
void cfconv_build(const float* __restrict__ W1,
                  const float* __restrict__ W2,
                  const float* __restrict__ mu,
                  const float* __restrict__ X,
                  unsigned short* __restrict__ tab16,
                  uint2* __restrict__ Xb,
                  float4* __restrict__ out4, int nout4,
                  float invScale, int nTabBlocks) {
    __shared__ __align__(16) float mulds[NB];
    __shared__ __align__(16) unsigned short h_lds[TB * HIDDEN];   // 16 KB swizzled; h then M

    const int t = threadIdx.x;

    if (blockIdx.x >= nTabBlocks) {        // ---- rider block ----
        int rid = (blockIdx.x - nTabBlocks) * 512 + t;
        int rstride = (gridDim.x - nTabBlocks) * 512;
        // zero the output
        for (int i = rid; i < nout4; i += rstride)
            out4[i] = make_float4(0.f, 0.f, 0.f, 0.f);
        // convert X -> quad-interleaved bf16 (slot i: v = i>>6, s = i&63)
        int total = V_TOTAL * 64;
        for (int i = rid; i < total; i += rstride) {
            int v = i >> 6, s = i & 63;
            const float* xr = X + (size_t)v * HIDDEN + s;
            unsigned u0 = f2bf(xr[0]);
            unsigned u1 = f2bf(xr[64]);
            unsigned u2 = f2bf(xr[128]);
            unsigned u3 = f2bf(xr[192]);
            uint2 wv; wv.x = u0 | (u1 << 16); wv.y = u2 | (u3 << 16);
            Xb[i] = wv;
        }
        return;
    }

    const int eb = blockIdx.x * TB;

    if (t < NB) mulds[t] = mu[t];
    __syncthreads();

    const int lane = t & 63;
    const int w = t >> 6;        // 0..7
    const int wr = w >> 2;       // row half 0..1 (rows 16*wr .. +16)
    const int wc = w & 3;        // col quarter 0..3 (cols 64*wc .. +64)
    const int lhi = lane >> 4;
    const int llo = lane & 15;

    // ---- GEMM1: h = relu(rbf @ W1); rbf in-register; W1 B-frags loaded
    //      directly from f32 global with in-register transpose+convert ----
    {
        float dm = mulds[1] - mulds[0];
        float ng = -1.0f / (dm * dm);
        float D0 = (float)(eb + 16 * wr + llo) * invScale;

        floatx4 acc[4];
        #pragma unroll
        for (int n = 0; n < 4; ++n) acc[n] = (floatx4)(0.0f);

        #pragma unroll
        for (int kc = 0; kc < 4; ++kc) {
            floatx4 mu0 = *(const floatx4*)(mulds + kc * 32 + lhi * 8);
            floatx4 mu1 = *(const floatx4*)(mulds + kc * 32 + lhi * 8 + 4);
            bf16x8 a, b[4];
            #pragma unroll
            for (int j = 0; j < 8; ++j) {
                float mv = (j < 4) ? mu0[j] : mu1[j - 4];
                float d = D0 - mv;
                a[j] = (__bf16)__expf(ng * d * d);
            }
            #pragma unroll
            for (int n = 0; n < 4; ++n) {
                const float* wb = W1 + (size_t)(kc * 32 + lhi * 8) * HIDDEN
                                     + wc * 64 + 16 * n + llo;
                #pragma unroll
                for (int j = 0; j < 8; ++j)
                    b[n][j] = (__bf16)wb[j * HIDDEN];
            }
            #pragma unroll
            for (int n = 0; n < 4; ++n)
                acc[n] = __builtin_amdgcn_mfma_f32_16x16x32_bf16(a, b[n], acc[n], 0, 0, 0);
        }

        char* hb = (char*)h_lds;
        #pragma unroll
        for (int n = 0; n < 4; ++n) {
            int col = wc * 64 + 16 * n + llo;
            #pragma unroll
            for (int r = 0; r < 4; ++r) {
                int row = 16 * wr + 4 * lhi + r;
                float v = fmaxf(acc[n][r], 0.0f);
                int byteoff = row * (HIDDEN * 2) + ((col * 2) ^ ((row & 7) << 4));
                *(__bf16*)(hb + byteoff) = (__bf16)v;
            }
        }
    }
    __syncthreads();

    // ---- GEMM2: M = relu(h @ W2), W2 B-frags direct from f32 global ----
    floatx4 acc[4];
    {
        #pragma unroll
        for (int n = 0; n < 4; ++n) acc[n] = (floatx4)(0.0f);

        const char* hb = (const char*)h_lds;
        const int arow = 16 * wr + llo;
        #pragma unroll
        for (int kc = 0; kc < 8; ++kc) {
            bf16x8 a = *(const bf16x8*)(hb + arow * (HIDDEN * 2)
                          + ((kc * 64 + 16 * lhi) ^ ((arow & 7) << 4)));
            bf16x8 b[4];
            #pragma unroll
            for (int n = 0; n < 4; ++n) {
                const float* wb = W2 + (size_t)(kc * 32 + lhi * 8) * HIDDEN
                                     + wc * 64 + 16 * n + llo;
                #pragma unroll
                for (int j = 0; j < 8; ++j)
                    b[n][j] = (__bf16)wb[j * HIDDEN];
            }
            #pragma unroll
            for (int n = 0; n < 4; ++n)
                acc[n] = __builtin_amdgcn_mfma_f32_16x16x32_bf16(a, b[n], acc[n], 0, 0, 0);
        }
    }
    __syncthreads();   // done reading h_lds

    // ---- store relu(M) bf16 into h_lds (swizzled) ----
    {
        char* hb = (char*)h_lds;
        #pragma unroll
        for (int n = 0; n < 4; ++n) {
            int col = wc * 64 + 16 * n + llo;
            #pragma unroll
            for (int r = 0; r < 4; ++r) {
                int row = 16 * wr + 4 * lhi + r;
                float v = fmaxf(acc[n][r], 0.0f);
                int byteoff = row * (HIDDEN * 2) + ((col * 2) ^ ((row & 7) << 4));
                *(__bf16*)(hb + byteoff) = (__bf16)v;
            }
        }
    }
    __syncthreads();

    // ---- write table rows quad-interleaved: thread (rg = t>>6, s = t&63)
    //      packs cols {s, s+64, s+128, s+192} of rows rg*4..rg*4+4 ----
    {
        const char* hb = (const char*)h_lds;
        const int s = t & 63;
        const int rg = t >> 6;
        #pragma unroll
        for (int rr = 0; rr < 4; ++rr) {
            int row = rg * 4 + rr;
            int sw = (row & 7) << 4;
            unsigned u0 = *(const unsigned short*)(hb + row * 512 + ((2 * s) ^ sw));
            unsigned u1 = *(const unsigned short*)(hb + row * 512 + ((2 * (s + 64)) ^ sw));
            unsigned u2 = *(const unsigned short*)(hb + row * 512 + ((2 * (s + 128)) ^ sw));
            unsigned u3 = *(const unsigned short*)(hb + row * 512 + ((2 * (s + 192)) ^ sw));
            uint2 wv; wv.x = u0 | (u1 << 16); wv.y = u2 | (u3 << 16);
            *(uint2*)((char*)tab16 + (size_t)(eb + row) * 512 + s * 8) = wv;
        }
    }
}

// Main: per edge, one tab dwordx2 + one Xb dwordx2 (both 64-lane dense) ->
// 4 fma -> run-length reduced atomic add. Wave q walks edge quarter
// [32q,32q+32); lane c owns columns c, c+64, c+128, c+192. 4-deep rotated
// A/B/C/D pipeline keeps 6 loads of other stages in flight across the
// run-flush branches.
__global__ __launch_bounds__(256)
void cfconv_gather(const char* __restrict__ Xb,
                   const float* __restrict__ R,
                   const char* __restrict__ tab,
                   const int* __restrict__ src,
                   const int* __restrict__ dest,
                   float* __restrict__ out,
                   float scale, int Tm1) {
    __shared__ __align__(16) uint4 meta[TEB];   // {dest, Xb byteoff, tab byteoff, 0}

    const int t = threadIdx.x;
    // XCD-aware swizzle: 2048 blocks, 8 XCDs -> contiguous 256-block chunk per XCD
    const int orig = blockIdx.x;
    const int cpx = gridDim.x >> 3;
    const int wg = (orig & 7) * cpx + (orig >> 3);
    const int eb = wg * TEB;

    if (t < TEB) {
        int e = eb + t;
        int s = src[e], d = dest[e];
        float dx = R[s * 3 + 0] - R[d * 3 + 0];
        float dy = R[s * 3 + 1] - R[d * 3 + 1];
        float dz = R[s * 3 + 2] - R[d * 3 + 2];
        float D = dx * dx + dy * dy + dz * dz;
        int i0 = min((int)(D * scale + 0.5f), Tm1);
        uint4 mrec;
        mrec.x = (unsigned)d;
        mrec.y = (unsigned)s * (HIDDEN * 2);           // byte offset into Xb (512B rows)
        mrec.z = (unsigned)i0 * (HIDDEN * 2);          // byte offset into tab (512B rows)
        mrec.w = 0u;
        meta[t] = mrec;
    }
    __syncthreads();

    const int q = t >> 6;                     // wave-uniform edge quarter
    const int rbase = q * 32;
    const int c = t & 63;                     // columns c + {0,64,128,192}
    const char* tabc = tab + c * 8;
    const char* Xc = Xb + c * 8;

    float a0 = 0.f, a1 = 0.f, a2 = 0.f, a3 = 0.f;

#define RF(x) __builtin_amdgcn_readfirstlane((int)(x))

#define FLUSH(dp) { \
        float* orow = out + (size_t)(dp) * HIDDEN + c; \
        unsafeAtomicAdd(orow, a0); \
        unsafeAtomicAdd(orow + 64, a1); \
        unsafeAtomicAdd(orow + 128, a2); \
        unsafeAtomicAdd(orow + 192, a3); \
        a0 = a1 = a2 = a3 = 0.f; }

#define DECL_STAGE(S) \
    int d##S; unsigned so##S, io##S; \
    uint2 qt##S, qx##S;

#define MET(S, idx) { \
    uint4 m_ = meta[rbase + ((idx) & 31)]; \
    d##S = RF(m_.x); so##S = (unsigned)RF(m_.y); io##S = (unsigned)RF(m_.z); }

#define LD(S) \
    qt##S = *(const uint2*)(tabc + io##S); \
    qx##S = *(const uint2*)(Xc + so##S);

#define CONSUME(S, nextidx) { \
    if (d##S != dprev) { FLUSH(dprev); dprev = d##S; } \
    union { unsigned u; float f; } mm_, xx_; \
    mm_.u = qt##S.x << 16;           xx_.u = qx##S.x << 16;           a0 = fmaf(mm_.f, xx_.f, a0); \
    mm_.u = qt##S.x & 0xffff0000u;   xx_.u = qx##S.x & 0xffff0000u;   a1 = fmaf(mm_.f, xx_.f, a1); \
    mm_.u = qt##S.y << 16;           xx_.u = qx##S.y << 16;           a2 = fmaf(mm_.f, xx_.f, a2); \
    mm_.u = qt##S.y & 0xffff0000u;   xx_.u = qx##S.y & 0xffff0000u;   a3 = fmaf(mm_.f, xx_.f, a3); \
    MET(S, nextidx); \
    LD(S); }

    DECL_STAGE(A) DECL_STAGE(B) DECL_STAGE(C) DECL_STAGE(D)

    MET(A, 0) LD(A)
    MET(B, 1) LD(B)
    MET(C, 2) LD(C)
    MET(D, 3) LD(D)
    int dprev = dA;

    #pragma unroll 2
    for (int rr = 0; rr < 8; ++rr) {
        int nb = rr * 4 + 4;       // next-group base (wraps harmlessly at tail)
        CONSUME(A, nb)
        CONSUME(B, nb + 1)
        CONSUME(C, nb + 2)
        CONSUME(D, nb + 3)
    }
    FLUSH(dprev);

#undef RF
#undef FLUSH
#undef DECL_STAGE
#undef MET
#undef LD
#undef CONSUME
}

extern "C" void kernel_launch(void* const* d_in, const int* in_sizes, int n_in,
                              void* d_out, int out_size, void* d_ws, size_t ws_size,
                              hipStream_t stream) {
    const float* X  = (const float*)d_in[0];
    const float* R  = (const float*)d_in[1];
    const float* W1 = (const float*)d_in[2];
    const float* W2 = (const float*)d_in[3];
    const float* mu = (const float*)d_in[4];
    const int* src  = (const int*)d_in[5];
    const int* dest = (const int*)d_in[6];
    float* out = (float*)d_out;

    // workspace layout: quad-interleaved NN table bf16[T*256] | Xb bf16[V*256]
    int T = 4096;
    const size_t xb_bytes = (size_t)V_TOTAL * HIDDEN * 2;
    if (ws_size > 0) {
        while (T > 64 && (size_t)T * HIDDEN * 2 + xb_bytes > ws_size) T >>= 1;
    }
    unsigned short* tab = (unsigned short*)d_ws;
    uint2* Xb = (uint2*)((char*)d_ws + (size_t)T * HIDDEN * 2);

    const float scale = (float)(T - 1) / R2MAX;
    const float invScale = R2MAX / (float)(T - 1);

    int nout4 = out_size / 4;
    int nTabBlocks = T / TB;
    int riderBlocks = 1024;

    cfconv_build<<<nTabBlocks + riderBlocks, 512, 0, stream>>>(
        W1, W2, mu, X, tab, Xb, (float4*)out, nout4, invScale, nTabBlocks);

    cfconv_gather<<<E_TOTAL / TEB, 256, 0, stream>>>((const char*)Xb, R, (const char*)tab,
                                                     src, dest, out, scale, T - 1);
}